// Round 6
// baseline (316.224 us; speedup 1.0000x reference)
//
#include <hip/hip_runtime.h>

// SobelLoss: loss = valid * (|gx| + |gy|), d = pred - tgt, separable Sobel:
//   v1[w] = d[h-1,w] + 2 d[h,w] + d[h+1,w];  gx = v1[w+1] - v1[w-1]
//   v2[w] = d[h+1,w] - d[h-1,w];             gy = v2[w-1] + 2 v2[w] + v2[w+1]
// valid = AND of mask 3x3 (zero-padded -> borders 0).
// Shapes: 12 images x 512 x 512 x 8 fp32, F innermost.
//
// R6: R5's wave-autonomous sliding window with the TA-byte model applied.
//   Binding resource (R1-R5 evidence): per-CU vmem byte throughput
//   (~20 B/cyc/CU, m13 copy ceiling) - NOT HBM BW, NOT occupancy.
//   (a) SEG_H 16 + peeled tail refills: exactly 18 rows loaded per 16
//       output rows (amp 1.5 -> 1.125).
//   (b) prefetch depth 3 (9 independent b128 in flight / 9 KB per wave)
//       to keep the vmem pipe fed through fold/shuffle/store phases.
//   Waves: 12*18*32 = 6912 = 27/CU.

constexpr int H = 512, W = 512, F = 8;
constexpr int IMAGES = 12;               // B*T
constexpr int SEG_H = 16;                // output rows per wave
constexpr int SEGS = H / SEG_H;          // 32
constexpr int STRIPS = 18;               // 18 * 30 output px >= 512
constexpr int ROWE = W * F;              // elements per image row
constexpr size_t IMG_ELEMS = (size_t)H * W * F;

__device__ __forceinline__ float4 sub4(float4 a, float4 b) {
    return make_float4(a.x - b.x, a.y - b.y, a.z - b.z, a.w - b.w);
}

__device__ __forceinline__ float4 shfl4(float4 v, int src) {
    float4 r;
    r.x = __shfl(v.x, src, 64);
    r.y = __shfl(v.y, src, 64);
    r.z = __shfl(v.z, src, 64);
    r.w = __shfl(v.w, src, 64);
    return r;
}

struct RowRaw { float4 p, t; int4 m; };

__device__ __forceinline__ RowRaw load_row(const float* __restrict__ pred,
                                           const float* __restrict__ tgt,
                                           const int*   __restrict__ mask,
                                           size_t colbase, int h) {
    const int hc = min(max(h, 0), H - 1);
    const size_t off = colbase + (size_t)hc * ROWE;
    RowRaw r;
    r.p = *(const float4*)(pred + off);
    r.t = *(const float4*)(tgt + off);
    r.m = *(const int4*)(mask + off);
    return r;
}

__device__ __forceinline__ void fold(const RowRaw& r, int hval, bool gpin,
                                     float4& d, unsigned& mv) {
    d = sub4(r.p, r.t);
    const unsigned pk = (unsigned)(r.m.x | (r.m.y << 1) | (r.m.z << 2) | (r.m.w << 3));
    mv = (hval >= 0 && hval < H && gpin) ? pk : 0u;
}

__global__ __launch_bounds__(256) void sobel_loss_kernel(
    const float* __restrict__ pred,
    const float* __restrict__ tgt,
    const int*   __restrict__ mask,
    float*       __restrict__ out)
{
    const int lane = threadIdx.x & 63;
    const int wid  = (blockIdx.x << 2) + (threadIdx.x >> 6);
    const int seg  = wid & (SEGS - 1);           // fastest: block = 4 consecutive segs
    const int t2   = wid >> 5;
    const int strip = t2 % STRIPS;
    const int img   = t2 / STRIPS;

    const int h0 = seg * SEG_H;
    const int ws = strip * 30;
    const int p  = lane >> 1;                    // staged px index 0..31
    const int qq = lane & 1;
    const int gp = ws - 1 + p;                   // staged global px (-1..541)
    const bool gpin = (gp >= 0) & (gp < W);
    const int gpc = min(max(gp, 0), W - 1);
    const size_t ibase = (size_t)img * IMG_ELEMS;
    const size_t colbase = ibase + (size_t)gpc * F + qq * 4;

    // Issue all 6 warmup rows (18 b128 loads) before any fold/wait.
    RowRaw r0 = load_row(pred, tgt, mask, colbase, h0 - 1);
    RowRaw r1 = load_row(pred, tgt, mask, colbase, h0);
    RowRaw r2 = load_row(pred, tgt, mask, colbase, h0 + 1);
    RowRaw s0 = load_row(pred, tgt, mask, colbase, h0 + 2);
    RowRaw s1 = load_row(pred, tgt, mask, colbase, h0 + 3);
    RowRaw s2 = load_row(pred, tgt, mask, colbase, h0 + 4);

    // Register ring: rows h-1, h, h+1.
    float4 dm1, d0c, dp1;
    unsigned mm1, m0c, mp1;
    fold(r0, h0 - 1, gpin, dm1, mm1);
    fold(r1, h0,     gpin, d0c, m0c);
    fold(r2, h0 + 1, gpin, dp1, mp1);

    const bool do_store = (p >= 1) & (p < 31) & (gp < W);
    const int lm2 = lane - 2, lp2 = lane + 2;    // edge-lane wrap values unused

    float* const outcol = out + ibase + (size_t)gp * F + qq * 4;

#pragma unroll
    for (int k = 0; k < SEG_H; ++k) {
        const int h = h0 + k;
        RowRaw& st = (k % 3 == 0) ? s0 : (k % 3 == 1) ? s1 : s2;

        // Vertical pass (registers only).
        const float4 v1 = make_float4(fmaf(2.f, d0c.x, dm1.x) + dp1.x,
                                      fmaf(2.f, d0c.y, dm1.y) + dp1.y,
                                      fmaf(2.f, d0c.z, dm1.z) + dp1.z,
                                      fmaf(2.f, d0c.w, dm1.w) + dp1.w);
        const float4 v2 = sub4(dp1, dm1);
        const unsigned mvv = mm1 & m0c & mp1;

        // Horizontal pass via cross-lane shuffle (neighbor px = lane +/- 2).
        const float4 v1l = shfl4(v1, lm2), v1r = shfl4(v1, lp2);
        const float4 v2l = shfl4(v2, lm2), v2r = shfl4(v2, lp2);
        const unsigned ml = (unsigned)__shfl((int)mvv, lm2, 64);
        const unsigned mr = (unsigned)__shfl((int)mvv, lp2, 64);
        const unsigned valid = mvv & ml & mr;

        float4 res;
        res.x = (valid & 1u) ? fabsf(v1r.x - v1l.x) + fabsf(fmaf(2.f, v2.x, v2l.x) + v2r.x) : 0.f;
        res.y = (valid & 2u) ? fabsf(v1r.y - v1l.y) + fabsf(fmaf(2.f, v2.y, v2l.y) + v2r.y) : 0.f;
        res.z = (valid & 4u) ? fabsf(v1r.z - v1l.z) + fabsf(fmaf(2.f, v2.z, v2l.z) + v2r.z) : 0.f;
        res.w = (valid & 8u) ? fabsf(v1r.w - v1l.w) + fabsf(fmaf(2.f, v2.w, v2l.w) + v2r.w) : 0.f;

        if (do_store)
            *(float4*)(outcol + (size_t)h * ROWE) = res;

        // Rotate ring; consume stage (row h+2, loaded 3 steps ago).
        // Last step's rotate is useless -> skipped (compile-time).
        if (k < SEG_H - 1) {
            dm1 = d0c; mm1 = m0c;
            d0c = dp1; m0c = mp1;
            fold(st, h + 2, gpin, dp1, mp1);
        }
        // Refill with row h+5; rows beyond h0+16 are never consumed, so the
        // last 4 refills are peeled off entirely (no wasted TA bytes).
        if (k <= SEG_H - 5) {
            st = load_row(pred, tgt, mask, colbase, h + 5);
        }
    }
}

extern "C" void kernel_launch(void* const* d_in, const int* in_sizes, int n_in,
                              void* d_out, int out_size, void* d_ws, size_t ws_size,
                              hipStream_t stream) {
    const float* pred = (const float*)d_in[0];
    const float* tgt  = (const float*)d_in[1];
    const int*   mask = (const int*)d_in[2];
    float*       out  = (float*)d_out;

    // 12 img * 18 strips * 32 segs = 6912 waves = 1728 blocks of 4 waves.
    const int blocks = IMAGES * STRIPS * SEGS / 4;
    sobel_loss_kernel<<<blocks, 256, 0, stream>>>(pred, tgt, mask, out);
}